// Round 4
// baseline (276.017 us; speedup 1.0000x reference)
//
#include <hip/hip_runtime.h>
#include <float.h>

// Problem constants (B=8, N=8192, D=3)
#define NB 8
#define NPTS 8192
#define TOTAL (NB * NPTS)             // 65536
#define BLK 256
#define WAVES 4
#define GROUPS 8                      // 32-col MFMA groups per wave
#define ADV_PER_WAVE (GROUPS * 32)    // 256
#define ADV_PER_BLOCK (WAVES * ADV_PER_WAVE)   // 1024
#define ADV_BLOCKS (TOTAL / ADV_PER_BLOCK)     // 64 (8 per batch)
#define OSPLIT 16                     // ori split -> partial mins
#define OSLICE (NPTS / OSPLIT)        // 512 ori records per block (16 KB LDS)
#define REC_SHORTS 16                 // 32 B per ori record
#define GRID_MAIN (ADV_BLOCKS * OSPLIT)        // 1024 blocks
#define BF16_ONE 0x3F80
#define MAGIC 0x1357BD09u             // not a byte-repeat: can't collide with ws poison

typedef short short8 __attribute__((ext_vector_type(8)));
typedef float floatx16 __attribute__((ext_vector_type(16)));

__device__ __forceinline__ unsigned short f2bf(float f) {   // RNE, no NaNs here
    unsigned int u = __float_as_uint(f);
    return (unsigned short)((u + 0x7FFFu + ((u >> 16) & 1u)) >> 16);
}
__device__ __forceinline__ float bf2f(unsigned short h) {
    return __uint_as_float(((unsigned int)h) << 16);
}
__device__ __forceinline__ float min3(float a, float b, float c) {
    return fminf(fminf(a, b), c);                 // -> v_min3_f32
}
// 16 accum values + carry-in um in 8 v_min3
__device__ __forceinline__ float fold16(floatx16 d, float um) {
    float t0 = min3(d[0], d[1], d[2]);
    float t1 = min3(d[3], d[4], d[5]);
    float t2 = min3(d[6], d[7], d[8]);
    float t3 = min3(d[9], d[10], d[11]);
    float t4 = min3(d[12], d[13], d[14]);
    float t5 = min3(t0, t1, d[15]);
    float t6 = min3(t2, t3, t4);
    return min3(t5, t6, um);
}

// ---- single graph-safe kernel: chamfer MFMA + flag-based completion + reduce ----
// Phase 1 (all 1024 blocks): identical to the 3-kernel passing version.
// Completion protocol (no grid.sync, no spin, poison-proof):
//   each block: __threadfence(); __syncthreads(); tid0 SEQ_CST-stores
//   flags[blockIdx.x]=MAGIC. Wave 0 then SEQ_CST-loads the 16 flags of its
//   advBlk group; the block whose flag store is last in the SC total order
//   must observe all 16 == MAGIC -> becomes reducer. Duplicate reducers are
//   idempotent (deterministic reduction of identical data). Blocks that see
//   an incomplete group simply exit -> no dispatch-order dependence.
// Reducer: min over 16 splits for its 1024 columns (64 KB), weighted sum ->
//   blocksum[advBlk]; same flag2 protocol over 64 groups; last reducer sums
//   64 values and writes out[0].
__global__ __launch_bounds__(BLK, 4) void chamfer_fused(const float* __restrict__ adv,
                                                        const float* __restrict__ ori,
                                                        const float* __restrict__ w,
                                                        float* __restrict__ partial,
                                                        unsigned* __restrict__ flags,
                                                        float* __restrict__ blocksum,
                                                        unsigned* __restrict__ flag2,
                                                        float* __restrict__ out) {
    __shared__ __align__(16) unsigned short lrec[OSLICE * REC_SHORTS];   // 16 KB
    __shared__ __align__(16) float advS[ADV_PER_BLOCK * 3];              // 12 KB
    __shared__ int doRed, doFin;
    __shared__ float ws4[WAVES];
    const int tid = threadIdx.x;
    const int wave = tid >> 6, lane = tid & 63;
    const int n32 = lane & 31, half = lane >> 5;
    const int advBlk = blockIdx.x >> 4;            // 0..63
    const int split = blockIdx.x & 15;
    const int b = advBlk >> 3;                     // 8 adv-blocks per batch
    const int advLocal = (advBlk & 7) * ADV_PER_BLOCK;

    if (tid < 128) {
        // ---- build 4 ori records from 3 float4 loads ----
        const float4* op = (const float4*)(ori + (size_t)(b * NPTS + split * OSLICE) * 3);
        float4 f0 = op[tid * 3 + 0], f1 = op[tid * 3 + 1], f2 = op[tid * 3 + 2];
        float px[4] = {f0.x, f0.w, f1.z, f2.y};
        float py[4] = {f0.y, f1.x, f1.w, f2.z};
        float pz[4] = {f0.z, f1.y, f2.x, f2.w};
#pragma unroll
        for (int r = 0; r < 4; r++) {
            float x = px[r], y = py[r], z = pz[r];
            unsigned short hx = f2bf(x), hy = f2bf(y), hz = f2bf(z);
            unsigned short lx = f2bf(x - bf2f(hx));
            unsigned short ly = f2bf(y - bf2f(hy));
            unsigned short lz = f2bf(z - bf2f(hz));
            float ro = fmaf(x, x, fmaf(y, y, z * z));
            unsigned short rh = f2bf(ro), rl = f2bf(ro - bf2f(rh));
            __align__(16) unsigned short rec[16] = {hx, hy, hz, lx, ly, lz, hx, hy,
                                                    hz, rh, rl, 0, 0, 0, 0, 0};
            float4* dst = (float4*)&lrec[(tid * 4 + r) * REC_SHORTS];
            dst[0] = ((float4*)rec)[0];
            dst[1] = ((float4*)rec)[1];
        }
    } else {
        // ---- stage 1024 adv points (768 float4) into LDS, coalesced ----
        const int tt = tid - 128;
        const float4* gadv4 = (const float4*)(adv + (size_t)b * NPTS * 3 + (size_t)advLocal * 3);
        float4* s4 = (float4*)advS;
#pragma unroll
        for (int i = 0; i < 6; i++) s4[tt + i * 128] = gadv4[tt + i * 128];
    }
    __syncthreads();

    // ---- B-fragments from LDS (lanes l and l+32 read same addr: broadcast) ----
    short8 bfr[GROUPS];
    float ra[GROUPS], um[GROUPS];
#pragma unroll
    for (int g = 0; g < GROUPS; g++) {
        int j = (wave * ADV_PER_WAVE + g * 32 + n32) * 3;
        float x = advS[j + 0], y = advS[j + 1], z = advS[j + 2];
        ra[g] = fmaf(x, x, fmaf(y, y, z * z));
        um[g] = FLT_MAX;
        unsigned short hx = f2bf(x), hy = f2bf(y), hz = f2bf(z);
        float fhx = bf2f(hx), fhy = bf2f(hy), fhz = bf2f(hz);
        unsigned short nhx = f2bf(-2.0f * fhx), nhy = f2bf(-2.0f * fhy), nhz = f2bf(-2.0f * fhz);
        unsigned short nlx = f2bf(-2.0f * bf2f(f2bf(x - fhx)));
        unsigned short nly = f2bf(-2.0f * bf2f(f2bf(y - fhy)));
        unsigned short nlz = f2bf(-2.0f * bf2f(f2bf(z - fhz)));
        __align__(16) unsigned short e[8] = {0, 0, 0, 0, 0, 0, 0, 0};
        if (half == 0) {
            e[0] = nhx; e[1] = nhy; e[2] = nhz;
            e[3] = nhx; e[4] = nhy; e[5] = nhz;
            e[6] = nlx; e[7] = nly;
        } else {
            e[0] = nlz; e[1] = BF16_ONE; e[2] = BF16_ONE;
        }
        bfr[g] = *(short8*)e;
    }

    const floatx16 zero = {0.f, 0.f, 0.f, 0.f, 0.f, 0.f, 0.f, 0.f,
                           0.f, 0.f, 0.f, 0.f, 0.f, 0.f, 0.f, 0.f};
    const int lsh = n32 * REC_SHORTS + half * 8;   // per-lane A-frag offset in a tile

    // ---- main loop: 16 ori-tiles; 1 ds_read_b128 feeds 8 MFMAs ----
#pragma unroll 2
    for (int t = 0; t < OSLICE / 32; t++) {
        short8 af = *(const short8*)&lrec[t * 32 * REC_SHORTS + lsh];
#pragma unroll
        for (int g = 0; g < GROUPS; g++) {
            floatx16 d = __builtin_amdgcn_mfma_f32_32x32x16_bf16(af, bfr[g], zero, 0, 0, 0);
            um[g] = fold16(d, um[g]);
        }
    }

    // rows per lane: half=0 -> {0-3,8-11,16-19,24-27}; shfl 32 folds the rest
#pragma unroll
    for (int g = 0; g < GROUPS; g++) {
        float v = fminf(um[g], __shfl_xor(um[g], 32, 64));
        if (half == 0) {
            int col = b * NPTS + advLocal + wave * ADV_PER_WAVE + g * 32 + n32;
            partial[(size_t)split * TOTAL + col] = ra[g] + v;
        }
    }

    // ---- completion announce (release) ----
    __threadfence();                 // agent-scope: partial writes visible
    __syncthreads();                 // all threads' fences done before flag
    if (tid == 0)
        __hip_atomic_store(&flags[blockIdx.x], MAGIC,
                           __ATOMIC_SEQ_CST, __HIP_MEMORY_SCOPE_AGENT);
    // ---- am I the last of my 16-block group? ----
    if (wave == 0) {
        unsigned f = MAGIC;
        if (lane < 16)
            f = __hip_atomic_load(&flags[advBlk * 16 + lane],
                                  __ATOMIC_SEQ_CST, __HIP_MEMORY_SCOPE_AGENT);
        unsigned long long ok = __ballot(f == MAGIC);
        if (lane == 0) doRed = (ok == ~0ULL) ? 1 : 0;
    }
    __syncthreads();
    if (!doRed) return;

    // ---- phase 2: reduce this advBlk's 1024 columns over 16 splits ----
    __threadfence();                 // acquire: see other blocks' partial
    const int colbase = b * NPTS + advLocal;
    float sum = 0.f;
#pragma unroll
    for (int i = 0; i < ADV_PER_BLOCK / BLK; i++) {      // 4 iters, coalesced
        int c = colbase + i * BLK + tid;
        float m = partial[c];
#pragma unroll
        for (int s = 1; s < OSPLIT; s++)
            m = fminf(m, partial[(size_t)s * TOTAL + c]);
        sum += m;
    }
#pragma unroll
    for (int s = 32; s > 0; s >>= 1) sum += __shfl_down(sum, s, 64);
    if (lane == 0) ws4[wave] = sum;
    __syncthreads();
    if (tid == 0) {
        blocksum[advBlk] = ((ws4[0] + ws4[1]) + (ws4[2] + ws4[3])) * w[b];
        __hip_atomic_store(&flag2[advBlk], MAGIC,
                           __ATOMIC_SEQ_CST, __HIP_MEMORY_SCOPE_AGENT);   // release
    }
    // ---- am I the last reducer? ----
    if (wave == 0) {
        unsigned f2 = __hip_atomic_load(&flag2[lane],
                                        __ATOMIC_SEQ_CST, __HIP_MEMORY_SCOPE_AGENT);
        unsigned long long ok2 = __ballot(f2 == MAGIC);
        if (lane == 0) doFin = (ok2 == ~0ULL) ? 1 : 0;
    }
    __syncthreads();
    if (doFin && wave == 0) {
        __threadfence();             // acquire: see all blocksum writes
        float v = blocksum[lane];    // 64 values, one per lane
#pragma unroll
        for (int s = 32; s > 0; s >>= 1) v += __shfl_down(v, s, 64);
        if (lane == 0) out[0] = v * (1.0f / (float)TOTAL);
    }
}

extern "C" void kernel_launch(void* const* d_in, const int* in_sizes, int n_in,
                              void* d_out, int out_size, void* d_ws, size_t ws_size,
                              hipStream_t stream) {
    const float* adv = (const float*)d_in[0];   // [8,8192,3] f32
    const float* ori = (const float*)d_in[1];   // [8,8192,3] f32
    const float* w   = (const float*)d_in[2];   // [8] f32
    float* out = (float*)d_out;
    float* partial = (float*)d_ws;                              // 4 MB
    unsigned* flags = (unsigned*)(partial + (size_t)OSPLIT * TOTAL);   // 1024 u32
    float* blocksum = (float*)(flags + GRID_MAIN);              // 64 f32
    unsigned* flag2 = (unsigned*)(blocksum + ADV_BLOCKS);       // 64 u32

    hipLaunchKernelGGL(chamfer_fused, dim3(GRID_MAIN), dim3(BLK), 0, stream,
                       adv, ori, w, partial, flags, blocksum, flag2, out);
}

// Round 5
// 81.540 us; speedup vs baseline: 3.3850x; 3.3850x over previous
//
#include <hip/hip_runtime.h>
#include <float.h>

// Problem constants (B=8, N=8192, D=3)
#define NB 8
#define NPTS 8192
#define TOTAL (NB * NPTS)             // 65536
#define BLK 256
#define WAVES 4
#define GROUPS 4                      // 32-col MFMA groups; all waves share the cols
#define ADVB (GROUPS * 32)            // 128 adv columns per block
#define BLOCKS (TOTAL / ADVB)         // 512 blocks -> 2 per CU
#define RREC 1024                     // ori records staged per round
#define ROUNDS (NPTS / RREC)          // 8
#define RECW (RREC / WAVES)           // 256 records per wave per round
#define TITER (RECW / 32)             // 8 MFMA tiles per wave per round
#define REC_SHORTS 16                 // 32 B per ori record
#define BF16_ONE 0x3F80

typedef short short8 __attribute__((ext_vector_type(8)));
typedef float floatx16 __attribute__((ext_vector_type(16)));

__device__ __forceinline__ unsigned short f2bf(float f) {   // RNE, no NaNs here
    unsigned int u = __float_as_uint(f);
    return (unsigned short)((u + 0x7FFFu + ((u >> 16) & 1u)) >> 16);
}
__device__ __forceinline__ float bf2f(unsigned short h) {
    return __uint_as_float(((unsigned int)h) << 16);
}
__device__ __forceinline__ float min3(float a, float b, float c) {
    return fminf(fminf(a, b), c);                 // -> v_min3_f32
}
// 16 accum values + carry-in um in 8 v_min3
__device__ __forceinline__ float fold16(floatx16 d, float um) {
    float t0 = min3(d[0], d[1], d[2]);
    float t1 = min3(d[3], d[4], d[5]);
    float t2 = min3(d[6], d[7], d[8]);
    float t3 = min3(d[9], d[10], d[11]);
    float t4 = min3(d[12], d[13], d[14]);
    float t5 = min3(t0, t1, d[15]);
    float t6 = min3(t2, t3, t4);
    return min3(t5, t6, um);
}

// ---- single kernel, NO cross-block data flow ----
// Each block owns 128 adv cols; streams ALL 8192 ori records of its batch
// through LDS (8 rounds x 1024 recs). Waves split each round's records
// (wave w -> recs [w*256, w*256+256)); cross-wave min is intra-block via LDS.
// Tail: one atomicAdd(out) per block (out is harness-memset to 0; atomics are
// device-coherent without fences -- round-4 showed fence protocols cost ~190us).
// K-slot map / record layout identical to the proven 3-kernel version:
//  k0..2: oh*(-2ah)  k3..5: ol*(-2ah)  k6..8: oh*(-2al)  k9: roh*1  k10: rol*1
// LDS swizzle: 16B-unit index u = m*2+h stored/read at u ^ ((m>>2)&7) --
// spreads the 8-way bank conflict (32 B record stride, 1.18M conflict cycles
// measured in round 4) across all 8 slot positions; write and read use the
// same XOR so data lands where it is read (both-sides-or-neither rule).
__global__ __launch_bounds__(BLK, 2) void chamfer_one(const float* __restrict__ adv,
                                                      const float* __restrict__ ori,
                                                      const float* __restrict__ w,
                                                      float* __restrict__ out) {
    __shared__ __align__(16) unsigned short lrec[RREC * REC_SHORTS];   // 32 KB
    __shared__ __align__(16) float advS[ADVB * 3];                     // 1.5 KB
    __shared__ float wmin[WAVES][ADVB];                                // 2 KB
    __shared__ float raS[ADVB];                                        // 0.5 KB
    __shared__ float ws4[WAVES];
    const int tid = threadIdx.x;
    const int wave = tid >> 6, lane = tid & 63;
    const int n32 = lane & 31, half = lane >> 5;
    const int b = blockIdx.x >> 6;                 // 64 blocks per batch
    const int advLocal = (blockIdx.x & 63) * ADVB;

    // ---- stage 128 adv points (96 float4), coalesced ----
    if (tid < (ADVB * 3 / 4)) {
        const float4* gadv4 = (const float4*)(adv + (size_t)(b * NPTS + advLocal) * 3);
        ((float4*)advS)[tid] = gadv4[tid];
    }
    __syncthreads();

    // ---- B-fragments (lanes l and l+32 read same addr: broadcast) ----
    short8 bfr[GROUPS];
    float ra[GROUPS], um[GROUPS];
#pragma unroll
    for (int g = 0; g < GROUPS; g++) {
        int j = (g * 32 + n32) * 3;
        float x = advS[j + 0], y = advS[j + 1], z = advS[j + 2];
        ra[g] = fmaf(x, x, fmaf(y, y, z * z));
        um[g] = FLT_MAX;
        unsigned short hx = f2bf(x), hy = f2bf(y), hz = f2bf(z);
        float fhx = bf2f(hx), fhy = bf2f(hy), fhz = bf2f(hz);
        unsigned short nhx = f2bf(-2.0f * fhx), nhy = f2bf(-2.0f * fhy), nhz = f2bf(-2.0f * fhz);
        unsigned short nlx = f2bf(-2.0f * bf2f(f2bf(x - fhx)));
        unsigned short nly = f2bf(-2.0f * bf2f(f2bf(y - fhy)));
        unsigned short nlz = f2bf(-2.0f * bf2f(f2bf(z - fhz)));
        __align__(16) unsigned short e[8] = {0, 0, 0, 0, 0, 0, 0, 0};
        if (half == 0) {
            e[0] = nhx; e[1] = nhy; e[2] = nhz;
            e[3] = nhx; e[4] = nhy; e[5] = nhz;
            e[6] = nlx; e[7] = nly;
        } else {
            e[0] = nlz; e[1] = BF16_ONE; e[2] = BF16_ONE;
        }
        bfr[g] = *(short8*)e;
    }

    const floatx16 zero = {0.f, 0.f, 0.f, 0.f, 0.f, 0.f, 0.f, 0.f,
                           0.f, 0.f, 0.f, 0.f, 0.f, 0.f, 0.f, 0.f};
    const float4* ori4 = (const float4*)(ori + (size_t)b * NPTS * 3);
    const int key = tid & 7;                       // swizzle key for this thread's recs

    // ---- 8 rounds: stage 1024 recs -> each wave computes its 256 ----
    for (int r = 0; r < ROUNDS; r++) {
        // issue global loads first: latency overlaps the barrier / prev compute
        float4 f0 = ori4[r * 768 + tid * 3 + 0];
        float4 f1 = ori4[r * 768 + tid * 3 + 1];
        float4 f2 = ori4[r * 768 + tid * 3 + 2];
        __syncthreads();                           // prev round's reads done
        float px[4] = {f0.x, f0.w, f1.z, f2.y};
        float py[4] = {f0.y, f1.x, f1.w, f2.z};
        float pz[4] = {f0.z, f1.y, f2.x, f2.w};
#pragma unroll
        for (int r4 = 0; r4 < 4; r4++) {
            float x = px[r4], y = py[r4], z = pz[r4];
            unsigned short hx = f2bf(x), hy = f2bf(y), hz = f2bf(z);
            unsigned short lx = f2bf(x - bf2f(hx));
            unsigned short ly = f2bf(y - bf2f(hy));
            unsigned short lz = f2bf(z - bf2f(hz));
            float ro = fmaf(x, x, fmaf(y, y, z * z));
            unsigned short rh = f2bf(ro), rl = f2bf(ro - bf2f(rh));
            __align__(16) unsigned short rec[16] = {hx, hy, hz, lx, ly, lz, hx, hy,
                                                    hz, rh, rl, 0, 0, 0, 0, 0};
            int m = tid * 4 + r4;                  // (m>>2)&7 == tid&7 == key
            *(float4*)((char*)lrec + (size_t)(((m * 2 + 0) ^ key) * 16)) = ((float4*)rec)[0];
            *(float4*)((char*)lrec + (size_t)(((m * 2 + 1) ^ key) * 16)) = ((float4*)rec)[1];
        }
        __syncthreads();                           // recs visible

        // ---- wave w: 8 tiles over recs [w*256, w*256+256) ----
#pragma unroll
        for (int t = 0; t < TITER; t++) {
            int u = ((wave * RECW + t * 32 + n32) * 2 + half) ^ ((n32 >> 2) & 7);
            short8 af = *(const short8*)((const char*)lrec + (size_t)u * 16);
#pragma unroll
            for (int g = 0; g < GROUPS; g++) {
                floatx16 d = __builtin_amdgcn_mfma_f32_32x32x16_bf16(af, bfr[g], zero, 0, 0, 0);
                um[g] = fold16(d, um[g]);
            }
        }
    }

    // ---- intra-wave: fold the two 32-lane halves; publish per-wave col mins ----
#pragma unroll
    for (int g = 0; g < GROUPS; g++) {
        float v = fminf(um[g], __shfl_xor(um[g], 32, 64));
        if (half == 0) {
            wmin[wave][g * 32 + n32] = v;
            if (wave == 0) raS[g * 32 + n32] = ra[g];
        }
    }
    __syncthreads();

    // ---- cross-wave min + per-block weighted sum; one atomicAdd per block ----
    float v = 0.f;
    if (tid < ADVB)
        v = raS[tid] + fminf(fminf(wmin[0][tid], wmin[1][tid]),
                             fminf(wmin[2][tid], wmin[3][tid]));
#pragma unroll
    for (int s = 32; s > 0; s >>= 1) v += __shfl_down(v, s, 64);
    if (lane == 0) ws4[wave] = v;
    __syncthreads();
    if (tid == 0)
        atomicAdd(out, ((ws4[0] + ws4[1]) + (ws4[2] + ws4[3])) * w[b] * (1.0f / (float)TOTAL));
}

extern "C" void kernel_launch(void* const* d_in, const int* in_sizes, int n_in,
                              void* d_out, int out_size, void* d_ws, size_t ws_size,
                              hipStream_t stream) {
    const float* adv = (const float*)d_in[0];   // [8,8192,3] f32
    const float* ori = (const float*)d_in[1];   // [8,8192,3] f32
    const float* w   = (const float*)d_in[2];   // [8] f32
    float* out = (float*)d_out;                 // memset to 0 by harness pre-launch

    hipLaunchKernelGGL(chamfer_one, dim3(BLOCKS), dim3(BLK), 0, stream,
                       adv, ori, w, out);
}

// Round 6
// 79.402 us; speedup vs baseline: 3.4762x; 1.0269x over previous
//
#include <hip/hip_runtime.h>
#include <float.h>

// Problem constants (B=8, N=8192, D=3)
#define NB 8
#define NPTS 8192
#define TOTAL (NB * NPTS)             // 65536
#define BLK 256
#define WAVES 4
#define GROUPS 2                      // 32-col MFMA groups per wave (occupancy play)
#define ADV_PER_WAVE (GROUPS * 32)    // 64
#define ADV_PER_BLOCK (WAVES * ADV_PER_WAVE)   // 256
#define ADV_BLOCKS (TOTAL / ADV_PER_BLOCK)     // 256 (32 per batch)
#define OSPLIT 16                     // ori split -> partial mins
#define OSLICE (NPTS / OSPLIT)        // 512 ori records per block (16 KB LDS)
#define REC_SHORTS 16                 // 32 B per ori record
#define GRID_MAIN (ADV_BLOCKS * OSPLIT)        // 4096 blocks
#define BF16_ONE 0x3F80
#define RED_BLOCKS 64
#define RED_THREADS 256

typedef short short8 __attribute__((ext_vector_type(8)));
typedef float floatx16 __attribute__((ext_vector_type(16)));

__device__ __forceinline__ unsigned short f2bf(float f) {   // RNE, no NaNs here
    unsigned int u = __float_as_uint(f);
    return (unsigned short)((u + 0x7FFFu + ((u >> 16) & 1u)) >> 16);
}
__device__ __forceinline__ float bf2f(unsigned short h) {
    return __uint_as_float(((unsigned int)h) << 16);
}
__device__ __forceinline__ float min3(float a, float b, float c) {
    return fminf(fminf(a, b), c);                 // -> v_min3_f32
}
// 16 accum values + carry-in um in 8 v_min3
__device__ __forceinline__ float fold16(floatx16 d, float um) {
    float t0 = min3(d[0], d[1], d[2]);
    float t1 = min3(d[3], d[4], d[5]);
    float t2 = min3(d[6], d[7], d[8]);
    float t3 = min3(d[9], d[10], d[11]);
    float t4 = min3(d[12], d[13], d[14]);
    float t5 = min3(t0, t1, d[15]);
    float t6 = min3(t2, t3, t4);
    return min3(t5, t6, um);
}

// ---- main: 32x32x16 bf16 MFMA brute force ----
// K-slot map (11 of 16 used):
//  k0..2: oh*(-2ah)  k3..5: ol*(-2ah)  k6..8: oh*(-2al)  k9: roh*1  k10: rol*1
// D[m][n] = ro_m - 2 dot(o_m, a_n)  (hi/lo split, exact in fp32 accum);
// d_n = ra_n + min_m D[m][n]  (ra exact fp32).
// Round-6 levers (diagnosis: latency-bound, both pipes <45%, occ 37%):
//  * GROUPS=2 + __launch_bounds__(256,6): 6 blocks/CU = 6 waves/SIMD (was 4),
//    LDS 6 x ~19.5KB = 117KB/CU, VGPR cap ~85 (live estimate 60-80).
//  * lrec XOR swizzle (verified correct in round 5): kills the measured
//    1.18M-cycle 8-way bank conflict on the 32 B record stride.
__global__ __launch_bounds__(BLK, 6) void chamfer_mfma(const float* __restrict__ adv,
                                                       const float* __restrict__ ori,
                                                       float* __restrict__ partial) {
    __shared__ __align__(16) unsigned short lrec[OSLICE * REC_SHORTS];   // 16 KB
    __shared__ __align__(16) float advS[ADV_PER_BLOCK * 3];              // 3 KB
    const int tid = threadIdx.x;
    const int wave = tid >> 6, lane = tid & 63;
    const int n32 = lane & 31, half = lane >> 5;
    const int advBlk = blockIdx.x >> 4;            // 0..255
    const int split = blockIdx.x & 15;
    const int b = advBlk >> 5;                     // 32 adv-blocks per batch
    const int advLocal = (advBlk & 31) * ADV_PER_BLOCK;

    if (tid < 128) {
        // ---- build 4 ori records from 3 float4 loads; swizzled LDS write ----
        const float4* op = (const float4*)(ori + (size_t)(b * NPTS + split * OSLICE) * 3);
        float4 f0 = op[tid * 3 + 0], f1 = op[tid * 3 + 1], f2 = op[tid * 3 + 2];
        float px[4] = {f0.x, f0.w, f1.z, f2.y};
        float py[4] = {f0.y, f1.x, f1.w, f2.z};
        float pz[4] = {f0.z, f1.y, f2.x, f2.w};
        const int key = tid & 7;                   // == ((tid*4+r)>>2)&7
#pragma unroll
        for (int r = 0; r < 4; r++) {
            float x = px[r], y = py[r], z = pz[r];
            unsigned short hx = f2bf(x), hy = f2bf(y), hz = f2bf(z);
            unsigned short lx = f2bf(x - bf2f(hx));
            unsigned short ly = f2bf(y - bf2f(hy));
            unsigned short lz = f2bf(z - bf2f(hz));
            float ro = fmaf(x, x, fmaf(y, y, z * z));
            unsigned short rh = f2bf(ro), rl = f2bf(ro - bf2f(rh));
            __align__(16) unsigned short rec[16] = {hx, hy, hz, lx, ly, lz, hx, hy,
                                                    hz, rh, rl, 0, 0, 0, 0, 0};
            int m = tid * 4 + r;                   // record index in slice
            *(float4*)((char*)lrec + (size_t)(((m * 2 + 0) ^ key) * 16)) = ((float4*)rec)[0];
            *(float4*)((char*)lrec + (size_t)(((m * 2 + 1) ^ key) * 16)) = ((float4*)rec)[1];
        }
    } else {
        // ---- stage 256 adv points (192 float4) into LDS, coalesced ----
        const int tt = tid - 128;
        const float4* gadv4 = (const float4*)(adv + (size_t)b * NPTS * 3 + (size_t)advLocal * 3);
        float4* s4 = (float4*)advS;
        if (tt < 192) s4[tt] = gadv4[tt];
        if (tt < 64) s4[tt + 128] = gadv4[tt + 128];
    }
    __syncthreads();

    // ---- B-fragments from LDS (lanes l and l+32 read same addr: broadcast) ----
    short8 bfr[GROUPS];
    float ra[GROUPS], um[GROUPS];
#pragma unroll
    for (int g = 0; g < GROUPS; g++) {
        int j = (wave * ADV_PER_WAVE + g * 32 + n32) * 3;
        float x = advS[j + 0], y = advS[j + 1], z = advS[j + 2];
        ra[g] = fmaf(x, x, fmaf(y, y, z * z));
        um[g] = FLT_MAX;
        unsigned short hx = f2bf(x), hy = f2bf(y), hz = f2bf(z);
        float fhx = bf2f(hx), fhy = bf2f(hy), fhz = bf2f(hz);
        unsigned short nhx = f2bf(-2.0f * fhx), nhy = f2bf(-2.0f * fhy), nhz = f2bf(-2.0f * fhz);
        unsigned short nlx = f2bf(-2.0f * bf2f(f2bf(x - fhx)));
        unsigned short nly = f2bf(-2.0f * bf2f(f2bf(y - fhy)));
        unsigned short nlz = f2bf(-2.0f * bf2f(f2bf(z - fhz)));
        __align__(16) unsigned short e[8] = {0, 0, 0, 0, 0, 0, 0, 0};
        if (half == 0) {
            e[0] = nhx; e[1] = nhy; e[2] = nhz;
            e[3] = nhx; e[4] = nhy; e[5] = nhz;
            e[6] = nlx; e[7] = nly;
        } else {
            e[0] = nlz; e[1] = BF16_ONE; e[2] = BF16_ONE;
        }
        bfr[g] = *(short8*)e;
    }

    const floatx16 zero = {0.f, 0.f, 0.f, 0.f, 0.f, 0.f, 0.f, 0.f,
                           0.f, 0.f, 0.f, 0.f, 0.f, 0.f, 0.f, 0.f};
    const int rkey = (n32 >> 2) & 7;               // read-side swizzle key

    // ---- main loop: 16 ori-tiles; swizzled ds_read_b128 feeds 2 MFMAs ----
#pragma unroll 4
    for (int t = 0; t < OSLICE / 32; t++) {
        int u = ((t * 32 + n32) * 2 + half) ^ rkey;
        short8 af = *(const short8*)((const char*)lrec + (size_t)u * 16);
#pragma unroll
        for (int g = 0; g < GROUPS; g++) {
            floatx16 d = __builtin_amdgcn_mfma_f32_32x32x16_bf16(af, bfr[g], zero, 0, 0, 0);
            um[g] = fold16(d, um[g]);
        }
    }

    // rows per lane: half=0 -> {0-3,8-11,16-19,24-27}; shfl 32 folds the rest
#pragma unroll
    for (int g = 0; g < GROUPS; g++) {
        float v = fminf(um[g], __shfl_xor(um[g], 32, 64));
        if (half == 0) {
            int col = b * NPTS + advLocal + wave * ADV_PER_WAVE + g * 32 + n32;
            partial[(size_t)split * TOTAL + col] = ra[g] + v;
        }
    }
}

// ---- reduce: min over 16 splits + weighted partial sums; no same-address atomics ----
__global__ __launch_bounds__(RED_THREADS) void reduce_mins(const float* __restrict__ partial,
                                                           const float* __restrict__ w,
                                                           float* __restrict__ blocksum) {
    const float4* p4 = (const float4*)partial;
    int g4 = blockIdx.x * RED_THREADS + threadIdx.x;   // 16384 float4 groups
    float4 m = p4[g4];
#pragma unroll
    for (int s = 1; s < OSPLIT; s++) {
        float4 v = p4[(size_t)s * (TOTAL / 4) + g4];
        m.x = fminf(m.x, v.x); m.y = fminf(m.y, v.y);
        m.z = fminf(m.z, v.z); m.w = fminf(m.w, v.w);
    }
    // 4 consecutive points share a batch (batch stride 8192 pts = 2048 float4)
    float v = ((m.x + m.y) + (m.z + m.w)) * w[g4 >> 11];
#pragma unroll
    for (int s = 32; s > 0; s >>= 1) v += __shfl_down(v, s, 64);
    __shared__ float wsum[RED_THREADS / 64];
    const int wave = threadIdx.x >> 6, lane = threadIdx.x & 63;
    if (lane == 0) wsum[wave] = v;
    __syncthreads();
    if (threadIdx.x == 0)
        blocksum[blockIdx.x] = (wsum[0] + wsum[1]) + (wsum[2] + wsum[3]);
}

// ---- final: sum 64 block partials in one wave, write out ----
__global__ __launch_bounds__(64) void final_sum(const float* __restrict__ blocksum,
                                                float* __restrict__ out) {
    float v = blocksum[threadIdx.x];
#pragma unroll
    for (int s = 32; s > 0; s >>= 1) v += __shfl_down(v, s, 64);
    if (threadIdx.x == 0) out[0] = v * (1.0f / (float)TOTAL);
}

extern "C" void kernel_launch(void* const* d_in, const int* in_sizes, int n_in,
                              void* d_out, int out_size, void* d_ws, size_t ws_size,
                              hipStream_t stream) {
    const float* adv = (const float*)d_in[0];   // [8,8192,3] f32
    const float* ori = (const float*)d_in[1];   // [8,8192,3] f32
    const float* w   = (const float*)d_in[2];   // [8] f32
    float* out = (float*)d_out;
    float* partial = (float*)d_ws;              // 16 * 64K floats = 4 MB
    float* blocksum = partial + (size_t)OSPLIT * TOTAL;   // 64 floats after partial

    hipLaunchKernelGGL(chamfer_mfma, dim3(GRID_MAIN), dim3(BLK), 0, stream,
                       adv, ori, partial);
    hipLaunchKernelGGL(reduce_mins, dim3(RED_BLOCKS), dim3(RED_THREADS), 0, stream,
                       partial, w, blocksum);
    hipLaunchKernelGGL(final_sum, dim3(1), dim3(64), 0, stream,
                       blocksum, out);
}